// Round 12
// baseline (101.550 us; speedup 1.0000x reference)
//
#include <hip/hip_runtime.h>
#include <hip/hip_bf16.h>

#define ALPHA 0.2f

typedef unsigned short ushort_t;
typedef unsigned int   uint_t;
typedef unsigned short ushort8 __attribute__((ext_vector_type(8)));
typedef uint_t uintv4 __attribute__((ext_vector_type(4)));
typedef float f32x4 __attribute__((ext_vector_type(4)));
typedef __bf16 bf16x8 __attribute__((ext_vector_type(8)));

// float -> bf16 bits, round-to-nearest-even (values are finite here)
__device__ __forceinline__ ushort_t f2bf(float f) {
  unsigned u = __float_as_uint(f);
  u += 0x7fffu + ((u >> 16) & 1u);
  return (ushort_t)(u >> 16);
}

// ---------------------------------------------------------------------------
// Kernel P: pack graph (0/1 floats) into a bitmask (4 MB -> 128 KB).
// Block 0 additionally computes u1 = W^T a1, u2 = W^T a2 (s = X.u).
// ---------------------------------------------------------------------------
__global__ __launch_bounds__(256) void gat_pack_kernel(
    const float* __restrict__ graph, const float* __restrict__ W,
    const float* __restrict__ avec, uint_t* __restrict__ gmask,
    float* __restrict__ u)
{
  const int row = blockIdx.x, t = threadIdx.x;
  __shared__ uint_t nibs[256];
  float4 g = ((const float4*)(graph + (size_t)row * 1024))[t];
  uint_t nib = (g.x != 0.f ? 1u : 0u) | (g.y != 0.f ? 2u : 0u) |
               (g.z != 0.f ? 4u : 0u) | (g.w != 0.f ? 8u : 0u);
  nibs[t] = nib;
  __syncthreads();
  if (t < 32) {
    uint_t wd = 0;
#pragma unroll
    for (int k = 0; k < 8; ++k) wd |= nibs[t * 8 + k] << (4 * k);
    gmask[(size_t)row * 32 + t] = wd;
  }
  if (row == 0 && t < 128) {             // u: 128 outputs (u1[64] | u2[64])
    const int k  = t & 63;
    const int ao = (t >> 6) * 128;
    float a0 = 0.f, a1 = 0.f, a2 = 0.f, a3 = 0.f;
    for (int d = 0; d < 128; d += 4) {
      a0 = fmaf(avec[ao + d + 0], W[(d + 0) * 64 + k], a0);
      a1 = fmaf(avec[ao + d + 1], W[(d + 1) * 64 + k], a1);
      a2 = fmaf(avec[ao + d + 2], W[(d + 2) * 64 + k], a2);
      a3 = fmaf(avec[ao + d + 3], W[(d + 3) * 64 + k], a3);
    }
    u[t] = (a0 + a1) + (a2 + a3);
  }
}

// ---------------------------------------------------------------------------
// Kernel A: h = X * W^T (fp32), hT[b][d][n] bf16, s1 = X.u1, s2 = X.u2.
// 32 n-rows per block, grid 1024 -> 4 blocks/CU.
// ---------------------------------------------------------------------------
__global__ __launch_bounds__(256) void gat_h_kernel(
    const float* __restrict__ inp, const float* __restrict__ W,
    const float* __restrict__ uvec, ushort_t* __restrict__ hT,
    float* __restrict__ s1, float* __restrict__ s2)
{
  const int b  = blockIdx.x >> 5;        // 32 chunks of 32 rows per batch
  const int n0 = (blockIdx.x & 31) << 5;
  const int t  = threadIdx.x;
  const int d  = t & 127;                // output channel
  const int nh = t >> 7;                 // which 16-row half

  __shared__ float    x_lds[32][68];     // 8.7 KB (pad: breaks bank striding)
  __shared__ float    u_lds[128];
  __shared__ ushort_t h_tile[128][40];   // 10 KB (80 B rows, 16B-aligned)

  float wreg[64];
  {
    const float4* wrow = (const float4*)(W + d * 64);
#pragma unroll
    for (int k = 0; k < 16; ++k) {
      float4 v = wrow[k];
      wreg[4*k+0] = v.x; wreg[4*k+1] = v.y; wreg[4*k+2] = v.z; wreg[4*k+3] = v.w;
    }
  }
  if (t < 128) u_lds[t] = uvec[t];

  {
    const float4* xsrc = (const float4*)(inp + ((size_t)b * 1024 + n0) * 64);
#pragma unroll
    for (int k = 0; k < 2; ++k) {
      const int g = k * 256 + t;         // 0..511 float4s
      const int n = g >> 4, c = g & 15;
      *(float4*)&x_lds[n][c * 4] = xsrc[g];
    }
  }
  __syncthreads();

  // h tile: thread (d, nh) computes 16 rows; X reads are wave-broadcast.
  for (int r = 0; r < 16; ++r) {
    const int n = nh * 16 + r;
    const float* xr = &x_lds[n][0];
    float ax = 0.f, ay = 0.f, az = 0.f, aw = 0.f;
#pragma unroll
    for (int k = 0; k < 16; ++k) {
      float4 xv = *(const float4*)&xr[4 * k];
      ax = fmaf(wreg[4*k+0], xv.x, ax);
      ay = fmaf(wreg[4*k+1], xv.y, ay);
      az = fmaf(wreg[4*k+2], xv.z, az);
      aw = fmaf(wreg[4*k+3], xv.w, aw);
    }
    h_tile[d][n] = f2bf((ax + ay) + (az + aw));
  }

  // s1/s2: thread t<64 -> row n=t&31, half t>>5
  if (t < 64) {
    const int n = t & 31, which = t >> 5;
    const float* xr = &x_lds[n][0];
    const float* uu = &u_lds[which * 64];
    float a0 = 0.f, a1 = 0.f, a2 = 0.f, a3 = 0.f;
#pragma unroll
    for (int k = 0; k < 16; ++k) {
      float4 xv = *(const float4*)&xr[4 * k];
      a0 = fmaf(xv.x, uu[4*k+0], a0);
      a1 = fmaf(xv.y, uu[4*k+1], a1);
      a2 = fmaf(xv.z, uu[4*k+2], a2);
      a3 = fmaf(xv.w, uu[4*k+3], a3);
    }
    const float sv = (a0 + a1) + (a2 + a3);
    if (which == 0) s1[(size_t)b * 1024 + n0 + n] = sv;
    else            s2[(size_t)b * 1024 + n0 + n] = sv;
  }
  __syncthreads();

  // coalesced bf16 hT writes: 2 iters x 256 chunks of 16 B
#pragma unroll
  for (int it = 0; it < 2; ++it) {
    const int idx = it * 256 + t;        // 0..511
    const int d2  = idx >> 2;
    const int ch  = (idx & 3) * 8;
    ushort8 v = *(const ushort8*)&h_tile[d2][ch];
    *(ushort8*)(hT + ((size_t)b * 128 + d2) * 1024 + n0 + ch) = v;
  }
}

// ---------------------------------------------------------------------------
// Kernel B: fused masked softmax + attention GEMM, BARRIER-FREE main loop,
// ZERO P-duplication: block = 128 thr (2 waves), 32 i-rows; wave w owns
// rows [i0+16w, i0+16w+16) x ALL 128 d.  Per j-32 tile, each wave:
//   - issues its 8 B-fragment loads (full 128-d hT tile; both waves read the
//     same 8 KB -> 2nd wave L1-hits; XCD swizzle keeps slab L2-resident)
//   - computes its A-fragment (P) in registers: lane l = row (l&15),
//     k-slots (l>>4)*8+e  (verified R6-R11 convention; B uses same k map)
//   - 8 MFMA (setprio-wrapped); loads issued at top are consumed here ->
//     exp phase (~300 cyc) covers the L1/L2 latency (T14 via compiler).
// den per-lane, completed by 2 shfl_xor; inv = den>0 ? 1/den : 0 (1 rcp).
// Prepass (all-LDS bitmask): exact masked row max -> Mi -> den >= 1.
// C/D layout: col = lane&15, row = (lane>>4)*4 + reg  [m89-verified].
// den from bf16-ROUNDED p via v_cvt_pk_bf16_f32 (RNE, matches f2bf).
// XCD swizzle: b = (bid&7)*4 + (bid>>8), ic = (bid>>3)&31 (bijective).
// ---------------------------------------------------------------------------
__global__ __launch_bounds__(128) void gat_attn_kernel(
    const uint_t* __restrict__ gmask, const ushort_t* __restrict__ hT,
    const float* __restrict__ s1g, const float* __restrict__ s2g,
    const float* __restrict__ bias, float* __restrict__ out)
{
  const int bid = blockIdx.x;          // 0..1023
  const int b   = (bid & 7) * 4 + (bid >> 8);   // 0..31, XCD-grouped
  const int ic  = (bid >> 3) & 31;     // 0..31
  const int i0  = ic << 5;             // 32 rows per block
  const int t   = threadIdx.x;         // 0..127
  const int w   = t >> 6;              // wave: 16-row half
  const int l   = t & 63;
  const int rl  = l & 15;              // lane's row / B d-row index
  const int js  = (l >> 4) * 8;        // k-chunk within the 32-tile

  __shared__ float  s2_lds[1024];      // 4 KB
  __shared__ uint_t mask_lds[32][33];  // 4.2 KB (pad: conflict-free)
  __shared__ float  red_part[32][4];
  __shared__ float  red_row[32];

  {
    const float4* src = (const float4*)(s2g + (size_t)b * 1024);
    ((float4*)s2_lds)[t]       = src[t];
    ((float4*)s2_lds)[t + 128] = src[t + 128];
  }
  {  // stage 32 rows x 32 mask words (256 uint4)
    const uint4* gsrc = (const uint4*)(gmask + (size_t)i0 * 32);
#pragma unroll
    for (int k2 = 0; k2 < 2; ++k2) {
      const int idx = t + k2 * 128;
      uint4 mv = gsrc[idx];
      const int mr = idx >> 3, mc = (idx & 7) * 4;
      mask_lds[mr][mc + 0] = mv.x; mask_lds[mr][mc + 1] = mv.y;
      mask_lds[mr][mc + 2] = mv.z; mask_lds[mr][mc + 3] = mv.w;
    }
  }
  __syncthreads();

  // ---- prepass: exact masked row max over 32 rows (all-LDS) ----
  {
    const int irow = t >> 2, bo = (t & 3) * 8;
    float mx = -1e30f;
    for (int jt = 0; jt < 32; ++jt) {
      const uint_t wd = mask_lds[irow][jt] >> bo;
      const float4 sA = *(const float4*)(s2_lds + jt * 32 + bo);
      const float4 sB = *(const float4*)(s2_lds + jt * 32 + bo + 4);
      if (wd & 1u)   mx = fmaxf(mx, sA.x);
      if (wd & 2u)   mx = fmaxf(mx, sA.y);
      if (wd & 4u)   mx = fmaxf(mx, sA.z);
      if (wd & 8u)   mx = fmaxf(mx, sA.w);
      if (wd & 16u)  mx = fmaxf(mx, sB.x);
      if (wd & 32u)  mx = fmaxf(mx, sB.y);
      if (wd & 64u)  mx = fmaxf(mx, sB.z);
      if (wd & 128u) mx = fmaxf(mx, sB.w);
    }
    red_part[irow][t & 3] = mx;
  }
  __syncthreads();
  if (t < 32)
    red_row[t] = fmaxf(fmaxf(red_part[t][0], red_part[t][1]),
                       fmaxf(red_part[t][2], red_part[t][3]));
  __syncthreads();

  const int ib = w * 16;               // wave's row base within the block
  const float s1v = s1g[(size_t)b * 1024 + i0 + ib + rl];
  const float tm  = s1v + red_row[ib + rl];
  const float Mi  = tm > 0.f ? tm : ALPHA * tm;   // exact row max of lrelu

  // B-fragment base: d = ds*16 + rl, j-chunk js
  const ushort_t* hb =
      hT + (size_t)b * 128 * 1024 + (size_t)rl * 1024 + js;

  f32x4 c[8];
#pragma unroll
  for (int ds = 0; ds < 8; ++ds) c[ds] = f32x4{0.f, 0.f, 0.f, 0.f};
  float den = 0.f;

  for (int jt = 0; jt < 32; ++jt) {
    const int j0 = jt * 32;
    // issue this tile's 8 B-fragment loads FIRST (consumed after exp phase)
    ushort8 bv[8];
#pragma unroll
    for (int ds = 0; ds < 8; ++ds)
      bv[ds] = *(const ushort8*)(hb + (size_t)ds * 16 * 1024 + j0);

    const uint_t wd = mask_lds[ib + rl][jt] >> js;
    const float4 sA = *(const float4*)(s2_lds + j0 + js);
    const float4 sB = *(const float4*)(s2_lds + j0 + js + 4);
    const float sv[8] = {sA.x, sA.y, sA.z, sA.w, sB.x, sB.y, sB.z, sB.w};
    float p[8];
#pragma unroll
    for (int e = 0; e < 8; ++e) {
      const float te = s1v + sv[e];
      const float v  = fmaxf(te, ALPHA * te);        // leaky relu
      p[e] = (((wd >> e) & 1u) && v != 0.f) ? __expf(v - Mi) : 0.f;
    }
    uint_t pk[4];
#pragma unroll
    for (int q = 0; q < 4; ++q) {
      asm("v_cvt_pk_bf16_f32 %0, %1, %2"
          : "=v"(pk[q]) : "v"(p[2 * q]), "v"(p[2 * q + 1]));
      den += __uint_as_float(pk[q] << 16) +
             __uint_as_float(pk[q] & 0xffff0000u);
    }
    const bf16x8 av =
        __builtin_bit_cast(bf16x8, (uintv4){pk[0], pk[1], pk[2], pk[3]});
    __builtin_amdgcn_s_setprio(1);
#pragma unroll
    for (int ds = 0; ds < 8; ++ds) {
      const bf16x8 bvv = __builtin_bit_cast(bf16x8, bv[ds]);
      c[ds] = __builtin_amdgcn_mfma_f32_16x16x32_bf16(av, bvv, c[ds], 0, 0, 0);
    }
    __builtin_amdgcn_s_setprio(0);
  }

  // complete den across the 4 k-groups (lanes with same l&15)
  den += __shfl_xor(den, 16);
  den += __shfl_xor(den, 32);
  const float inv = den > 0.f ? 1.f / den : 0.f;   // den==0 -> val = bias

#pragma unroll
  for (int ds = 0; ds < 8; ++ds) {
    const int col = ds * 16 + rl;
    const float bc = bias[col];
#pragma unroll
    for (int r = 0; r < 4; ++r) {
      const int rr   = (l >> 4) * 4 + r;       // 0..15 within wave tile
      const int row  = ib + rr;
      const float iv = __shfl(inv, rr);        // lane rr holds inv[row]
      const float val = fmaf(c[ds][r], iv, bc);
      out[((size_t)b * 1024 + i0 + row) * 128 + col] = val;
    }
  }
}

// ---------------------------------------------------------------------------
extern "C" void kernel_launch(void* const* d_in, const int* in_sizes, int n_in,
                              void* d_out, int out_size, void* d_ws, size_t ws_size,
                              hipStream_t stream) {
  (void)in_sizes; (void)n_in; (void)out_size; (void)ws_size;
  const float* inp   = (const float*)d_in[0];   // (32,1024,64) f32
  const float* graph = (const float*)d_in[1];   // (1024,1024)  f32
  const float* W     = (const float*)d_in[2];   // (128,64)     f32
  const float* bias  = (const float*)d_in[3];   // (128,)       f32
  const float* avec  = (const float*)d_in[4];   // (256,1)      f32
  float* out = (float*)d_out;                   // (32,1024,128) f32

  // workspace: hT bf16 8 MB | s1 128 KB | s2 128 KB | u 4 KB | gmask 128 KB
  char* ws = (char*)d_ws;
  ushort_t* hT = (ushort_t*)ws;
  float* s1    = (float*)(ws + (size_t)8 * 1024 * 1024);
  float* s2    = s1 + 32 * 1024;
  float* u     = s2 + 32 * 1024;
  uint_t* gm   = (uint_t*)(ws + (size_t)8 * 1024 * 1024 + 512 * 1024);

  gat_pack_kernel<<<1024, 256, 0, stream>>>(graph, W, avec, gm, u);
  gat_h_kernel<<<1024, 256, 0, stream>>>(inp, W, u, hT, s1, s2);
  gat_attn_kernel<<<1024, 128, 0, stream>>>(gm, hT, s1, s2, bias, out);
}

// Round 14
// 75.405 us; speedup vs baseline: 1.3467x; 1.3467x over previous
//
#include <hip/hip_runtime.h>
#include <hip/hip_bf16.h>

#define ALPHA 0.2f

typedef unsigned short ushort_t;
typedef unsigned int   uint_t;
typedef unsigned short ushort8 __attribute__((ext_vector_type(8)));
typedef uint_t uintv4 __attribute__((ext_vector_type(4)));
typedef float f32x4 __attribute__((ext_vector_type(4)));
typedef __bf16 bf16x8 __attribute__((ext_vector_type(8)));

// float -> bf16 bits, round-to-nearest-even (values are finite here)
__device__ __forceinline__ ushort_t f2bf(float f) {
  unsigned u = __float_as_uint(f);
  u += 0x7fffu + ((u >> 16) & 1u);
  return (ushort_t)(u >> 16);
}

// ---------------------------------------------------------------------------
// Kernel P: pack graph (0/1 floats) into a bitmask (4 MB -> 128 KB).
// Block 0 additionally computes u1 = W^T a1, u2 = W^T a2 (s = X.u).
// ---------------------------------------------------------------------------
__global__ __launch_bounds__(256) void gat_pack_kernel(
    const float* __restrict__ graph, const float* __restrict__ W,
    const float* __restrict__ avec, uint_t* __restrict__ gmask,
    float* __restrict__ u)
{
  const int row = blockIdx.x, t = threadIdx.x;
  __shared__ uint_t nibs[256];
  float4 g = ((const float4*)(graph + (size_t)row * 1024))[t];
  uint_t nib = (g.x != 0.f ? 1u : 0u) | (g.y != 0.f ? 2u : 0u) |
               (g.z != 0.f ? 4u : 0u) | (g.w != 0.f ? 8u : 0u);
  nibs[t] = nib;
  __syncthreads();
  if (t < 32) {
    uint_t wd = 0;
#pragma unroll
    for (int k = 0; k < 8; ++k) wd |= nibs[t * 8 + k] << (4 * k);
    gmask[(size_t)row * 32 + t] = wd;
  }
  if (row == 0 && t < 128) {             // u: 128 outputs (u1[64] | u2[64])
    const int k  = t & 63;
    const int ao = (t >> 6) * 128;
    float a0 = 0.f, a1 = 0.f, a2 = 0.f, a3 = 0.f;
    for (int d = 0; d < 128; d += 4) {
      a0 = fmaf(avec[ao + d + 0], W[(d + 0) * 64 + k], a0);
      a1 = fmaf(avec[ao + d + 1], W[(d + 1) * 64 + k], a1);
      a2 = fmaf(avec[ao + d + 2], W[(d + 2) * 64 + k], a2);
      a3 = fmaf(avec[ao + d + 3], W[(d + 3) * 64 + k], a3);
    }
    u[t] = (a0 + a1) + (a2 + a3);
  }
}

// ---------------------------------------------------------------------------
// Kernel A: h = X * W^T (fp32), hT[b][d][n] bf16, s1 = X.u1, s2 = X.u2.
// 32 n-rows per block, grid 1024 -> 4 blocks/CU.
// ---------------------------------------------------------------------------
__global__ __launch_bounds__(256) void gat_h_kernel(
    const float* __restrict__ inp, const float* __restrict__ W,
    const float* __restrict__ uvec, ushort_t* __restrict__ hT,
    float* __restrict__ s1, float* __restrict__ s2)
{
  const int b  = blockIdx.x >> 5;        // 32 chunks of 32 rows per batch
  const int n0 = (blockIdx.x & 31) << 5;
  const int t  = threadIdx.x;
  const int d  = t & 127;                // output channel
  const int nh = t >> 7;                 // which 16-row half

  __shared__ float    x_lds[32][68];     // 8.7 KB (pad: breaks bank striding)
  __shared__ float    u_lds[128];
  __shared__ ushort_t h_tile[128][40];   // 10 KB (80 B rows, 16B-aligned)

  float wreg[64];
  {
    const float4* wrow = (const float4*)(W + d * 64);
#pragma unroll
    for (int k = 0; k < 16; ++k) {
      float4 v = wrow[k];
      wreg[4*k+0] = v.x; wreg[4*k+1] = v.y; wreg[4*k+2] = v.z; wreg[4*k+3] = v.w;
    }
  }
  if (t < 128) u_lds[t] = uvec[t];

  {
    const float4* xsrc = (const float4*)(inp + ((size_t)b * 1024 + n0) * 64);
#pragma unroll
    for (int k = 0; k < 2; ++k) {
      const int g = k * 256 + t;         // 0..511 float4s
      const int n = g >> 4, c = g & 15;
      *(float4*)&x_lds[n][c * 4] = xsrc[g];
    }
  }
  __syncthreads();

  // h tile: thread (d, nh) computes 16 rows; X reads are wave-broadcast.
  for (int r = 0; r < 16; ++r) {
    const int n = nh * 16 + r;
    const float* xr = &x_lds[n][0];
    float ax = 0.f, ay = 0.f, az = 0.f, aw = 0.f;
#pragma unroll
    for (int k = 0; k < 16; ++k) {
      float4 xv = *(const float4*)&xr[4 * k];
      ax = fmaf(wreg[4*k+0], xv.x, ax);
      ay = fmaf(wreg[4*k+1], xv.y, ay);
      az = fmaf(wreg[4*k+2], xv.z, az);
      aw = fmaf(wreg[4*k+3], xv.w, aw);
    }
    h_tile[d][n] = f2bf((ax + ay) + (az + aw));
  }

  // s1/s2: thread t<64 -> row n=t&31, half t>>5
  if (t < 64) {
    const int n = t & 31, which = t >> 5;
    const float* xr = &x_lds[n][0];
    const float* uu = &u_lds[which * 64];
    float a0 = 0.f, a1 = 0.f, a2 = 0.f, a3 = 0.f;
#pragma unroll
    for (int k = 0; k < 16; ++k) {
      float4 xv = *(const float4*)&xr[4 * k];
      a0 = fmaf(xv.x, uu[4*k+0], a0);
      a1 = fmaf(xv.y, uu[4*k+1], a1);
      a2 = fmaf(xv.z, uu[4*k+2], a2);
      a3 = fmaf(xv.w, uu[4*k+3], a3);
    }
    const float sv = (a0 + a1) + (a2 + a3);
    if (which == 0) s1[(size_t)b * 1024 + n0 + n] = sv;
    else            s2[(size_t)b * 1024 + n0 + n] = sv;
  }
  __syncthreads();

  // coalesced bf16 hT writes: 2 iters x 256 chunks of 16 B
#pragma unroll
  for (int it = 0; it < 2; ++it) {
    const int idx = it * 256 + t;        // 0..511
    const int d2  = idx >> 2;
    const int ch  = (idx & 3) * 8;
    ushort8 v = *(const ushort8*)&h_tile[d2][ch];
    *(ushort8*)(hT + ((size_t)b * 128 + d2) * 1024 + n0 + ch) = v;
  }
}

// ---------------------------------------------------------------------------
// Kernel B: fused masked softmax + attention GEMM.
// Block = 256 thr (4 waves), 64 i-rows; wave (rg, jh) owns 32 rows
// (rg half) x 128 d x 512 j (jh half).  Per j-32 tile each wave:
//   - 8 B-frag loads, double-buffered one iter ahead (R10's amortization:
//     8 loads feed 16 MFMA = 2 A-frags x 8 B-frags)
//   - 16 exps -> 2 A-frags in registers (each (row,j) exp computed exactly
//     ONCE grid-wide: j-halves disjoint)
// Lane map: row rl=l&15 (+16 for 2nd frag), k-slots (l>>4)*8+e  (verified
// R6-R12 convention; B uses the same k map -> k-layout independent).
// C/D layout: col = lane&15, row = (lane>>4)*4 + reg  [m89-verified].
// den from bf16-ROUNDED p via v_cvt_pk_bf16_f32 (RNE).
// Epilogue: jh=1 dumps partial c/den to LDS (132-pad: 2-way banks = free),
// one barrier, jh=0 sums and writes.  Prepass: exact masked row max -> Mi
// -> den >= 1 (no underflow).  No barriers in the main loop.
// ---------------------------------------------------------------------------
__global__ __launch_bounds__(256) void gat_attn_kernel(
    const uint_t* __restrict__ gmask, const ushort_t* __restrict__ hT,
    const float* __restrict__ s1g, const float* __restrict__ s2g,
    const float* __restrict__ bias, float* __restrict__ out)
{
  const int ic = blockIdx.x;           // 0..15
  const int b  = blockIdx.y;           // 0..31
  const int i0 = ic << 6;              // 64 rows per block
  const int t  = threadIdx.x;
  const int w  = t >> 6;
  const int rg = w & 1;                // row-group (32 rows)
  const int jh = w >> 1;               // j-half (512 j)
  const int l  = t & 63;
  const int rl = l & 15;               // lane's row / B d-row index
  const int js = (l >> 4) * 8;         // k-chunk within the 32-tile

  __shared__ float  s2_lds[1024];      // 4 KB
  __shared__ uint_t mask_lds[64][33];  // 8.4 KB (pad: conflict-free)
  __shared__ float  red_part[64][4];
  __shared__ float  red_row[64];
  __shared__ float  credu[64][132];    // 33.8 KB (pad 132: 2-way banks)
  __shared__ float  den_lds[64];

  ((float4*)s2_lds)[t] = ((const float4*)(s2g + (size_t)b * 1024))[t];
  {  // stage 64 rows x 32 mask words (512 uint4)
    const uint4* gsrc = (const uint4*)(gmask + (size_t)i0 * 32);
#pragma unroll
    for (int k2 = 0; k2 < 2; ++k2) {
      const int idx = t + k2 * 256;
      uint4 mv = gsrc[idx];
      const int mr = idx >> 3, mc = (idx & 7) * 4;
      mask_lds[mr][mc + 0] = mv.x; mask_lds[mr][mc + 1] = mv.y;
      mask_lds[mr][mc + 2] = mv.z; mask_lds[mr][mc + 3] = mv.w;
    }
  }
  __syncthreads();

  // ---- prepass: exact masked row max over 64 rows (all-LDS) ----
  {
    const int irow = t >> 2, bo = (t & 3) * 8;
    float mx = -1e30f;
    for (int jt = 0; jt < 32; ++jt) {
      const uint_t wd = mask_lds[irow][jt] >> bo;
      const float4 sA = *(const float4*)(s2_lds + jt * 32 + bo);
      const float4 sB = *(const float4*)(s2_lds + jt * 32 + bo + 4);
      if (wd & 1u)   mx = fmaxf(mx, sA.x);
      if (wd & 2u)   mx = fmaxf(mx, sA.y);
      if (wd & 4u)   mx = fmaxf(mx, sA.z);
      if (wd & 8u)   mx = fmaxf(mx, sA.w);
      if (wd & 16u)  mx = fmaxf(mx, sB.x);
      if (wd & 32u)  mx = fmaxf(mx, sB.y);
      if (wd & 64u)  mx = fmaxf(mx, sB.z);
      if (wd & 128u) mx = fmaxf(mx, sB.w);
    }
    red_part[irow][t & 3] = mx;
  }
  __syncthreads();
  if (t < 64)
    red_row[t] = fmaxf(fmaxf(red_part[t][0], red_part[t][1]),
                       fmaxf(red_part[t][2], red_part[t][3]));
  __syncthreads();

  const int ib = rg * 32;              // wave's row base within the block
  const float s1lo = s1g[(size_t)b * 1024 + i0 + ib + rl];
  const float s1hi = s1g[(size_t)b * 1024 + i0 + ib + 16 + rl];
  const float tl = s1lo + red_row[ib + rl];
  const float th = s1hi + red_row[ib + 16 + rl];
  const float Milo = tl > 0.f ? tl : ALPHA * tl;   // exact row max of lrelu
  const float Mihi = th > 0.f ? th : ALPHA * th;

  // B-fragment base: d = ds*16 + rl, j = jh*512 + jt*32 + js
  const ushort_t* hb =
      hT + (size_t)b * 128 * 1024 + (size_t)rl * 1024 + jh * 512 + js;

  f32x4 c[2][8];
#pragma unroll
  for (int is = 0; is < 2; ++is)
#pragma unroll
    for (int ds = 0; ds < 8; ++ds) c[is][ds] = f32x4{0.f, 0.f, 0.f, 0.f};
  float den_lo = 0.f, den_hi = 0.f;

  ushort8 bv[8], nb[8];
#pragma unroll
  for (int ds = 0; ds < 8; ++ds)
    bv[ds] = *(const ushort8*)(hb + (size_t)ds * 16 * 1024);

  for (int jt = 0; jt < 16; ++jt) {
    const int j0 = jt * 32;
    const int jn = (jt + 1 < 16) ? j0 + 32 : j0;   // clamped prefetch
#pragma unroll
    for (int ds = 0; ds < 8; ++ds)
      nb[ds] = *(const ushort8*)(hb + (size_t)ds * 16 * 1024 + jn);

    const uint_t wlo = mask_lds[ib + rl][jh * 16 + jt] >> js;
    const uint_t whi = mask_lds[ib + 16 + rl][jh * 16 + jt] >> js;
    const float4 sA = *(const float4*)(s2_lds + jh * 512 + j0 + js);
    const float4 sB = *(const float4*)(s2_lds + jh * 512 + j0 + js + 4);
    const float sv[8] = {sA.x, sA.y, sA.z, sA.w, sB.x, sB.y, sB.z, sB.w};
    float plo[8], phi[8];
#pragma unroll
    for (int e = 0; e < 8; ++e) {
      float te = s1lo + sv[e];
      float v  = fmaxf(te, ALPHA * te);              // leaky relu
      plo[e] = (((wlo >> e) & 1u) && v != 0.f) ? __expf(v - Milo) : 0.f;
      te = s1hi + sv[e];
      v  = fmaxf(te, ALPHA * te);
      phi[e] = (((whi >> e) & 1u) && v != 0.f) ? __expf(v - Mihi) : 0.f;
    }
    uint_t pkl[4], pkh[4];
#pragma unroll
    for (int q = 0; q < 4; ++q) {
      asm("v_cvt_pk_bf16_f32 %0, %1, %2"
          : "=v"(pkl[q]) : "v"(plo[2 * q]), "v"(plo[2 * q + 1]));
      asm("v_cvt_pk_bf16_f32 %0, %1, %2"
          : "=v"(pkh[q]) : "v"(phi[2 * q]), "v"(phi[2 * q + 1]));
      den_lo += __uint_as_float(pkl[q] << 16) +
                __uint_as_float(pkl[q] & 0xffff0000u);
      den_hi += __uint_as_float(pkh[q] << 16) +
                __uint_as_float(pkh[q] & 0xffff0000u);
    }
    const bf16x8 av0 =
        __builtin_bit_cast(bf16x8, (uintv4){pkl[0], pkl[1], pkl[2], pkl[3]});
    const bf16x8 av1 =
        __builtin_bit_cast(bf16x8, (uintv4){pkh[0], pkh[1], pkh[2], pkh[3]});
    __builtin_amdgcn_s_setprio(1);
#pragma unroll
    for (int ds = 0; ds < 8; ++ds) {
      const bf16x8 bvv = __builtin_bit_cast(bf16x8, bv[ds]);
      c[0][ds] = __builtin_amdgcn_mfma_f32_16x16x32_bf16(av0, bvv, c[0][ds], 0, 0, 0);
      c[1][ds] = __builtin_amdgcn_mfma_f32_16x16x32_bf16(av1, bvv, c[1][ds], 0, 0, 0);
    }
    __builtin_amdgcn_s_setprio(0);
#pragma unroll
    for (int ds = 0; ds < 8; ++ds) bv[ds] = nb[ds];
  }

  // complete den across the 4 k-groups (lanes with same l&15)
  den_lo += __shfl_xor(den_lo, 16); den_lo += __shfl_xor(den_lo, 32);
  den_hi += __shfl_xor(den_hi, 16); den_hi += __shfl_xor(den_hi, 32);

  // ---- cross-wave (j-half) reduction ----
  if (jh == 1) {
#pragma unroll
    for (int is = 0; is < 2; ++is)
#pragma unroll
      for (int ds = 0; ds < 8; ++ds)
#pragma unroll
        for (int r = 0; r < 4; ++r)
          credu[ib + is * 16 + (l >> 4) * 4 + r][ds * 16 + rl] = c[is][ds][r];
    if (l < 16) {
      den_lds[ib + rl]      = den_lo;
      den_lds[ib + 16 + rl] = den_hi;
    }
  }
  __syncthreads();
  if (jh == 0) {
    const float dl = den_lo + den_lds[ib + rl];
    const float dh = den_hi + den_lds[ib + 16 + rl];
    const float inv_lo = dl > 0.f ? 1.f / dl : 0.f;
    const float inv_hi = dh > 0.f ? 1.f / dh : 0.f;
#pragma unroll
    for (int ds = 0; ds < 8; ++ds) {
      const int col = ds * 16 + rl;
      const float bc = bias[col];
#pragma unroll
      for (int is = 0; is < 2; ++is) {
#pragma unroll
        for (int r = 0; r < 4; ++r) {
          const int rr  = (l >> 4) * 4 + r;
          const int row = ib + is * 16 + rr;
          const float cc = c[is][ds][r] + credu[row][col];
          const float iv = __shfl(is ? inv_hi : inv_lo, rr);
          out[((size_t)b * 1024 + i0 + row) * 128 + col] = fmaf(cc, iv, bc);
        }
      }
    }
  }
}

// ---------------------------------------------------------------------------
extern "C" void kernel_launch(void* const* d_in, const int* in_sizes, int n_in,
                              void* d_out, int out_size, void* d_ws, size_t ws_size,
                              hipStream_t stream) {
  (void)in_sizes; (void)n_in; (void)out_size; (void)ws_size;
  const float* inp   = (const float*)d_in[0];   // (32,1024,64) f32
  const float* graph = (const float*)d_in[1];   // (1024,1024)  f32
  const float* W     = (const float*)d_in[2];   // (128,64)     f32
  const float* bias  = (const float*)d_in[3];   // (128,)       f32
  const float* avec  = (const float*)d_in[4];   // (256,1)      f32
  float* out = (float*)d_out;                   // (32,1024,128) f32

  // workspace: hT bf16 8 MB | s1 128 KB | s2 128 KB | u 4 KB | gmask 128 KB
  char* ws = (char*)d_ws;
  ushort_t* hT = (ushort_t*)ws;
  float* s1    = (float*)(ws + (size_t)8 * 1024 * 1024);
  float* s2    = s1 + 32 * 1024;
  float* u     = s2 + 32 * 1024;
  uint_t* gm   = (uint_t*)(ws + (size_t)8 * 1024 * 1024 + 512 * 1024);

  gat_pack_kernel<<<1024, 256, 0, stream>>>(graph, W, avec, gm, u);
  gat_h_kernel<<<1024, 256, 0, stream>>>(inp, W, u, hT, s1, s2);
  gat_attn_kernel<<<dim3(16, 32), 256, 0, stream>>>(gm, hT, s1, s2, bias, out);
}

// Round 17
// 74.512 us; speedup vs baseline: 1.3629x; 1.0120x over previous
//
#include <hip/hip_runtime.h>
#include <hip/hip_bf16.h>

#define ALPHA 0.2f

typedef unsigned short ushort_t;
typedef unsigned int   uint_t;
typedef unsigned short ushort8 __attribute__((ext_vector_type(8)));
typedef uint_t uintv4 __attribute__((ext_vector_type(4)));
typedef float f32x4 __attribute__((ext_vector_type(4)));
typedef __bf16 bf16x8 __attribute__((ext_vector_type(8)));

// float -> bf16 bits, round-to-nearest-even (values are finite here)
__device__ __forceinline__ ushort_t f2bf(float f) {
  unsigned u = __float_as_uint(f);
  u += 0x7fffu + ((u >> 16) & 1u);
  return (ushort_t)(u >> 16);
}

// ---------------------------------------------------------------------------
// Kernel P: pack graph (0/1 floats) into a bitmask (4 MB -> 128 KB).
// Block 0 additionally computes u1 = W^T a1, u2 = W^T a2 (s = X.u).
// ---------------------------------------------------------------------------
__global__ __launch_bounds__(256) void gat_pack_kernel(
    const float* __restrict__ graph, const float* __restrict__ W,
    const float* __restrict__ avec, uint_t* __restrict__ gmask,
    float* __restrict__ u)
{
  const int row = blockIdx.x, t = threadIdx.x;
  __shared__ uint_t nibs[256];
  float4 g = ((const float4*)(graph + (size_t)row * 1024))[t];
  uint_t nib = (g.x != 0.f ? 1u : 0u) | (g.y != 0.f ? 2u : 0u) |
               (g.z != 0.f ? 4u : 0u) | (g.w != 0.f ? 8u : 0u);
  nibs[t] = nib;
  __syncthreads();
  if (t < 32) {
    uint_t wd = 0;
#pragma unroll
    for (int k = 0; k < 8; ++k) wd |= nibs[t * 8 + k] << (4 * k);
    gmask[(size_t)row * 32 + t] = wd;
  }
  if (row == 0 && t < 128) {             // u: 128 outputs (u1[64] | u2[64])
    const int k  = t & 63;
    const int ao = (t >> 6) * 128;
    float a0 = 0.f, a1 = 0.f, a2 = 0.f, a3 = 0.f;
    for (int d = 0; d < 128; d += 4) {
      a0 = fmaf(avec[ao + d + 0], W[(d + 0) * 64 + k], a0);
      a1 = fmaf(avec[ao + d + 1], W[(d + 1) * 64 + k], a1);
      a2 = fmaf(avec[ao + d + 2], W[(d + 2) * 64 + k], a2);
      a3 = fmaf(avec[ao + d + 3], W[(d + 3) * 64 + k], a3);
    }
    u[t] = (a0 + a1) + (a2 + a3);
  }
}

// ---------------------------------------------------------------------------
// Kernel A: h = X * W^T (fp32), hT[b][d][n] bf16, s1 = X.u1, s2 = X.u2.
// 32 n-rows per block, grid 1024 -> 4 blocks/CU.  (unchanged, verified)
// ---------------------------------------------------------------------------
__global__ __launch_bounds__(256) void gat_h_kernel(
    const float* __restrict__ inp, const float* __restrict__ W,
    const float* __restrict__ uvec, ushort_t* __restrict__ hT,
    float* __restrict__ s1, float* __restrict__ s2)
{
  const int b  = blockIdx.x >> 5;        // 32 chunks of 32 rows per batch
  const int n0 = (blockIdx.x & 31) << 5;
  const int t  = threadIdx.x;
  const int d  = t & 127;                // output channel
  const int nh = t >> 7;                 // which 16-row half

  __shared__ float    x_lds[32][68];     // 8.7 KB (pad: breaks bank striding)
  __shared__ float    u_lds[128];
  __shared__ ushort_t h_tile[128][40];   // 10 KB (80 B rows, 16B-aligned)

  float wreg[64];
  {
    const float4* wrow = (const float4*)(W + d * 64);
#pragma unroll
    for (int k = 0; k < 16; ++k) {
      float4 v = wrow[k];
      wreg[4*k+0] = v.x; wreg[4*k+1] = v.y; wreg[4*k+2] = v.z; wreg[4*k+3] = v.w;
    }
  }
  if (t < 128) u_lds[t] = uvec[t];

  {
    const float4* xsrc = (const float4*)(inp + ((size_t)b * 1024 + n0) * 64);
#pragma unroll
    for (int k = 0; k < 2; ++k) {
      const int g = k * 256 + t;         // 0..511 float4s
      const int n = g >> 4, c = g & 15;
      *(float4*)&x_lds[n][c * 4] = xsrc[g];
    }
  }
  __syncthreads();

  // h tile: thread (d, nh) computes 16 rows; X reads are wave-broadcast.
  for (int r = 0; r < 16; ++r) {
    const int n = nh * 16 + r;
    const float* xr = &x_lds[n][0];
    float ax = 0.f, ay = 0.f, az = 0.f, aw = 0.f;
#pragma unroll
    for (int k = 0; k < 16; ++k) {
      float4 xv = *(const float4*)&xr[4 * k];
      ax = fmaf(wreg[4*k+0], xv.x, ax);
      ay = fmaf(wreg[4*k+1], xv.y, ay);
      az = fmaf(wreg[4*k+2], xv.z, az);
      aw = fmaf(wreg[4*k+3], xv.w, aw);
    }
    h_tile[d][n] = f2bf((ax + ay) + (az + aw));
  }

  // s1/s2: thread t<64 -> row n=t&31, half t>>5
  if (t < 64) {
    const int n = t & 31, which = t >> 5;
    const float* xr = &x_lds[n][0];
    const float* uu = &u_lds[which * 64];
    float a0 = 0.f, a1 = 0.f, a2 = 0.f, a3 = 0.f;
#pragma unroll
    for (int k = 0; k < 16; ++k) {
      float4 xv = *(const float4*)&xr[4 * k];
      a0 = fmaf(xv.x, uu[4*k+0], a0);
      a1 = fmaf(xv.y, uu[4*k+1], a1);
      a2 = fmaf(xv.z, uu[4*k+2], a2);
      a3 = fmaf(xv.w, uu[4*k+3], a3);
    }
    const float sv = (a0 + a1) + (a2 + a3);
    if (which == 0) s1[(size_t)b * 1024 + n0 + n] = sv;
    else            s2[(size_t)b * 1024 + n0 + n] = sv;
  }
  __syncthreads();

  // coalesced bf16 hT writes: 2 iters x 256 chunks of 16 B
#pragma unroll
  for (int it = 0; it < 2; ++it) {
    const int idx = it * 256 + t;        // 0..511
    const int d2  = idx >> 2;
    const int ch  = (idx & 3) * 8;
    ushort8 v = *(const ushort8*)&h_tile[d2][ch];
    *(ushort8*)(hT + ((size_t)b * 128 + d2) * 1024 + n0 + ch) = v;
  }
}

// ---------------------------------------------------------------------------
// Kernel B: fused masked softmax + attention GEMM (R14 numerics, 3 latency
// cuts).  Block = 256 thr (4 waves), 64 i-rows; wave (rg, jh) owns 32 rows
// x 128 d x 512 j.  Changes vs R14 (all numerics-preserving):
//  (1) den VIA ONES-MFMA: mfma(P_frag, ones) -> exact fp32 row-sums of the
//      ROUNDED P land per-lane in the C/D slots the epilogue divides.
//  (2) prepass with 4 independent fmax chains (cuts the 32-iter LDS-latency
//      chain 4x).
//  (3) main loop prefetches next iter's LDS operands (mask+s2) before the
//      exp phase, like the existing global B prefetch.
// P per-element: p = exp(lrelu(s1+s2) - Mi), exponent <= 0 (PROVEN safe).
// Lane map / C/D layout / epilogue: as verified R6-R14.
// ---------------------------------------------------------------------------
__global__ __launch_bounds__(256) void gat_attn_kernel(
    const uint_t* __restrict__ gmask, const ushort_t* __restrict__ hT,
    const float* __restrict__ s1g, const float* __restrict__ s2g,
    const float* __restrict__ bias, float* __restrict__ out)
{
  const int ic = blockIdx.x;           // 0..15
  const int b  = blockIdx.y;           // 0..31
  const int i0 = ic << 6;              // 64 rows per block
  const int t  = threadIdx.x;
  const int w  = t >> 6;
  const int rg = w & 1;                // row-group (32 rows)
  const int jh = w >> 1;               // j-half (512 j)
  const int l  = t & 63;
  const int rl = l & 15;               // lane's row / B d-row index
  const int js = (l >> 4) * 8;         // k-chunk within the 32-tile

  __shared__ float  s2_lds[1024];      // 4 KB
  __shared__ uint_t mask_lds[64][33];  // 8.4 KB (pad: conflict-free)
  __shared__ float  red_part[64][4];
  __shared__ float  red_row[64];
  __shared__ float  credu[64][132];    // 33.8 KB (pad 132: 2-way banks)
  __shared__ float  den_lds[64];

  ((float4*)s2_lds)[t] = ((const float4*)(s2g + (size_t)b * 1024))[t];
  {  // stage 64 rows x 32 mask words (512 uint4)
    const uint4* gsrc = (const uint4*)(gmask + (size_t)i0 * 32);
#pragma unroll
    for (int k2 = 0; k2 < 2; ++k2) {
      const int idx = t + k2 * 256;
      uint4 mv = gsrc[idx];
      const int mr = idx >> 3, mc = (idx & 7) * 4;
      mask_lds[mr][mc + 0] = mv.x; mask_lds[mr][mc + 1] = mv.y;
      mask_lds[mr][mc + 2] = mv.z; mask_lds[mr][mc + 3] = mv.w;
    }
  }
  __syncthreads();

  // ---- prepass: exact masked row max, 4 independent chains ----
  {
    const int irow = t >> 2, bo = (t & 3) * 8;
    float mxa[4] = {-1e30f, -1e30f, -1e30f, -1e30f};
    for (int jt4 = 0; jt4 < 8; ++jt4) {
#pragma unroll
      for (int q = 0; q < 4; ++q) {
        const int jt = jt4 * 4 + q;
        const uint_t wd = mask_lds[irow][jt] >> bo;
        const float4 sA = *(const float4*)(s2_lds + jt * 32 + bo);
        const float4 sB = *(const float4*)(s2_lds + jt * 32 + bo + 4);
        float m = mxa[q];
        if (wd & 1u)   m = fmaxf(m, sA.x);
        if (wd & 2u)   m = fmaxf(m, sA.y);
        if (wd & 4u)   m = fmaxf(m, sA.z);
        if (wd & 8u)   m = fmaxf(m, sA.w);
        if (wd & 16u)  m = fmaxf(m, sB.x);
        if (wd & 32u)  m = fmaxf(m, sB.y);
        if (wd & 64u)  m = fmaxf(m, sB.z);
        if (wd & 128u) m = fmaxf(m, sB.w);
        mxa[q] = m;
      }
    }
    red_part[irow][t & 3] = fmaxf(fmaxf(mxa[0], mxa[1]), fmaxf(mxa[2], mxa[3]));
  }
  __syncthreads();
  if (t < 64)
    red_row[t] = fmaxf(fmaxf(red_part[t][0], red_part[t][1]),
                       fmaxf(red_part[t][2], red_part[t][3]));
  __syncthreads();

  const int ib = rg * 32;              // wave's row base within the block
  const float s1lo = s1g[(size_t)b * 1024 + i0 + ib + rl];
  const float s1hi = s1g[(size_t)b * 1024 + i0 + ib + 16 + rl];
  const float tl = s1lo + red_row[ib + rl];
  const float th = s1hi + red_row[ib + 16 + rl];
  const float Milo = tl > 0.f ? tl : ALPHA * tl;   // exact row max of lrelu
  const float Mihi = th > 0.f ? th : ALPHA * th;

  // B-fragment base: d = ds*16 + rl, j = jh*512 + jt*32 + js
  const ushort_t* hb =
      hT + (size_t)b * 128 * 1024 + (size_t)rl * 1024 + jh * 512 + js;

  f32x4 c[2][8];
#pragma unroll
  for (int is = 0; is < 2; ++is)
#pragma unroll
    for (int ds = 0; ds < 8; ++ds) c[is][ds] = f32x4{0.f, 0.f, 0.f, 0.f};
  f32x4 cden[2] = {f32x4{0.f, 0.f, 0.f, 0.f}, f32x4{0.f, 0.f, 0.f, 0.f}};
  const bf16x8 bones = __builtin_bit_cast(
      bf16x8, (uintv4){0x3F803F80u, 0x3F803F80u, 0x3F803F80u, 0x3F803F80u});

  ushort8 bv[8], nb[8];
#pragma unroll
  for (int ds = 0; ds < 8; ++ds)
    bv[ds] = *(const ushort8*)(hb + (size_t)ds * 16 * 1024);

  // preload iter-0 LDS operands
  uint_t wlo_c = mask_lds[ib + rl][jh * 16];
  uint_t whi_c = mask_lds[ib + 16 + rl][jh * 16];
  float4 sA_c = *(const float4*)(s2_lds + jh * 512 + js);
  float4 sB_c = *(const float4*)(s2_lds + jh * 512 + js + 4);

  for (int jt = 0; jt < 16; ++jt) {
    const int j0 = jt * 32;
    const int jn = (jt + 1 < 16) ? j0 + 32 : j0;   // clamped prefetch
#pragma unroll
    for (int ds = 0; ds < 8; ++ds)
      nb[ds] = *(const ushort8*)(hb + (size_t)ds * 16 * 1024 + jn);
    // LDS operand prefetch for next iter (clamped)
    const int jtn = (jt + 1 < 16) ? jt + 1 : jt;
    const uint_t wlo_n = mask_lds[ib + rl][jh * 16 + jtn];
    const uint_t whi_n = mask_lds[ib + 16 + rl][jh * 16 + jtn];
    const float4 sA_n = *(const float4*)(s2_lds + jh * 512 + jtn * 32 + js);
    const float4 sB_n = *(const float4*)(s2_lds + jh * 512 + jtn * 32 + js + 4);

    const uint_t wlo = wlo_c >> js;
    const uint_t whi = whi_c >> js;
    const float sv[8] = {sA_c.x, sA_c.y, sA_c.z, sA_c.w,
                         sB_c.x, sB_c.y, sB_c.z, sB_c.w};
    float plo[8], phi[8];
#pragma unroll
    for (int e = 0; e < 8; ++e) {
      float te = s1lo + sv[e];
      float v  = fmaxf(te, ALPHA * te);              // leaky relu
      plo[e] = (((wlo >> e) & 1u) && v != 0.f) ? __expf(v - Milo) : 0.f;
      te = s1hi + sv[e];
      v  = fmaxf(te, ALPHA * te);
      phi[e] = (((whi >> e) & 1u) && v != 0.f) ? __expf(v - Mihi) : 0.f;
    }
    uint_t pkl[4], pkh[4];
#pragma unroll
    for (int q = 0; q < 4; ++q) {
      asm("v_cvt_pk_bf16_f32 %0, %1, %2"
          : "=v"(pkl[q]) : "v"(plo[2 * q]), "v"(plo[2 * q + 1]));
      asm("v_cvt_pk_bf16_f32 %0, %1, %2"
          : "=v"(pkh[q]) : "v"(phi[2 * q]), "v"(phi[2 * q + 1]));
    }
    const bf16x8 av0 =
        __builtin_bit_cast(bf16x8, (uintv4){pkl[0], pkl[1], pkl[2], pkl[3]});
    const bf16x8 av1 =
        __builtin_bit_cast(bf16x8, (uintv4){pkh[0], pkh[1], pkh[2], pkh[3]});
    __builtin_amdgcn_s_setprio(1);
#pragma unroll
    for (int ds = 0; ds < 8; ++ds) {
      const bf16x8 bvv = __builtin_bit_cast(bf16x8, bv[ds]);
      c[0][ds] = __builtin_amdgcn_mfma_f32_16x16x32_bf16(av0, bvv, c[0][ds], 0, 0, 0);
      c[1][ds] = __builtin_amdgcn_mfma_f32_16x16x32_bf16(av1, bvv, c[1][ds], 0, 0, 0);
    }
    // den = P . ones : exact fp32 row-sums of ROUNDED P, lands per-lane
    cden[0] = __builtin_amdgcn_mfma_f32_16x16x32_bf16(av0, bones, cden[0], 0, 0, 0);
    cden[1] = __builtin_amdgcn_mfma_f32_16x16x32_bf16(av1, bones, cden[1], 0, 0, 0);
    __builtin_amdgcn_s_setprio(0);
#pragma unroll
    for (int ds = 0; ds < 8; ++ds) bv[ds] = nb[ds];
    wlo_c = wlo_n; whi_c = whi_n; sA_c = sA_n; sB_c = sB_n;
  }

  // ---- cross-wave (j-half) reduction ----
  if (jh == 1) {
#pragma unroll
    for (int is = 0; is < 2; ++is)
#pragma unroll
      for (int ds = 0; ds < 8; ++ds)
#pragma unroll
        for (int r = 0; r < 4; ++r)
          credu[ib + is * 16 + (l >> 4) * 4 + r][ds * 16 + rl] = c[is][ds][r];
    if (rl == 0) {   // col-lanes hold identical den rows; one writes
#pragma unroll
      for (int is = 0; is < 2; ++is)
#pragma unroll
        for (int r = 0; r < 4; ++r)
          den_lds[ib + is * 16 + (l >> 4) * 4 + r] = cden[is][r];
    }
  }
  __syncthreads();
  if (jh == 0) {
    float inv[2][4];
#pragma unroll
    for (int is = 0; is < 2; ++is)
#pragma unroll
      for (int r = 0; r < 4; ++r) {
        const float dt = cden[is][r] + den_lds[ib + is * 16 + (l >> 4) * 4 + r];
        inv[is][r] = dt > 0.f ? 1.f / dt : 0.f;
      }
#pragma unroll
    for (int ds = 0; ds < 8; ++ds) {
      const int col = ds * 16 + rl;
      const float bc = bias[col];
#pragma unroll
      for (int is = 0; is < 2; ++is) {
#pragma unroll
        for (int r = 0; r < 4; ++r) {
          const int row = ib + is * 16 + (l >> 4) * 4 + r;
          const float cc = c[is][ds][r] + credu[row][col];
          out[((size_t)b * 1024 + i0 + row) * 128 + col] =
              fmaf(cc, inv[is][r], bc);
        }
      }
    }
  }
}

// ---------------------------------------------------------------------------
extern "C" void kernel_launch(void* const* d_in, const int* in_sizes, int n_in,
                              void* d_out, int out_size, void* d_ws, size_t ws_size,
                              hipStream_t stream) {
  (void)in_sizes; (void)n_in; (void)out_size; (void)ws_size;
  const float* inp   = (const float*)d_in[0];   // (32,1024,64) f32
  const float* graph = (const float*)d_in[1];   // (1024,1024)  f32
  const float* W     = (const float*)d_in[2];   // (128,64)     f32
  const float* bias  = (const float*)d_in[3];   // (128,)       f32
  const float* avec  = (const float*)d_in[4];   // (256,1)      f32
  float* out = (float*)d_out;                   // (32,1024,128) f32

  // workspace: hT bf16 8 MB | s1 128 KB | s2 128 KB | u 4 KB | gmask 128 KB
  char* ws = (char*)d_ws;
  ushort_t* hT = (ushort_t*)ws;
  float* s1    = (float*)(ws + (size_t)8 * 1024 * 1024);
  float* s2    = s1 + 32 * 1024;
  float* u     = s2 + 32 * 1024;
  uint_t* gm   = (uint_t*)(ws + (size_t)8 * 1024 * 1024 + 512 * 1024);

  gat_pack_kernel<<<1024, 256, 0, stream>>>(graph, W, avec, gm, u);
  gat_h_kernel<<<1024, 256, 0, stream>>>(inp, W, u, hT, s1, s2);
  gat_attn_kernel<<<dim3(16, 32), 256, 0, stream>>>(gm, hT, s1, s2, bias, out);
}